// Round 19
// baseline (175.415 us; speedup 1.0000x reference)
//
#include <hip/hip_runtime.h>

typedef __attribute__((ext_vector_type(4))) float f32x4;
typedef __attribute__((ext_vector_type(8))) __bf16 bf16x8;
typedef __attribute__((ext_vector_type(4))) __bf16 bf16x4;

#define DEV __device__ __forceinline__

DEV f32x4 mfma_bf16(bf16x8 a, bf16x8 b, f32x4 c) {
  return __builtin_amdgcn_mfma_f32_16x16x32_bf16(a, b, c, 0, 0, 0);
}

DEV void glds16(const void* gp, void* lp) {
  __builtin_amdgcn_global_load_lds((const __attribute__((address_space(1))) void*)gp,
                                   (__attribute__((address_space(3))) void*)lp, 16, 0, 0);
}

DEV float fast_exp2(float x) {
#if __has_builtin(__builtin_amdgcn_exp2f)
  return __builtin_amdgcn_exp2f(x);
#else
  float r;
  asm("v_exp_f32 %0, %1" : "=v"(r) : "v"(x));
  return r;
#endif
}

#define SB0() __builtin_amdgcn_sched_barrier(0)

// ---------------- fused f32->bf16 conversions ----------------
__global__ __launch_bounds__(256) void cvt_all(const float* __restrict__ hs,
                                               const float* __restrict__ qw,
                                               const float* __restrict__ kw,
                                               const float* __restrict__ vw,
                                               const float* __restrict__ ow,
                                               __bf16* __restrict__ oX,
                                               __bf16* __restrict__ oQ,
                                               __bf16* __restrict__ oK,
                                               __bf16* __restrict__ oV,
                                               __bf16* __restrict__ oO) {
  const int blk = blockIdx.x;
  if (blk < 3840) {
    long long e = ((long long)blk * 256 + threadIdx.x) * 8;
    bf16x8 o = {};
    if (e < 7680000) {
      const f32x4* ip = (const f32x4*)(hs + e);
      f32x4 a = ip[0], b = ip[1];
#pragma unroll
      for (int j = 0; j < 4; ++j) { o[j] = (__bf16)a[j]; o[j + 4] = (__bf16)b[j]; }
    }
    *(bf16x8*)(oX + e) = o;
  } else {
    const int wb = blk - 3840;
    const int which = wb / 800;
    const int bb = wb - which * 800;
    const float* in = which == 0 ? qw : which == 1 ? kw : which == 2 ? vw : ow;
    __bf16* out = which == 0 ? oQ : which == 1 ? oK : which == 2 ? oV : oO;
    long long e = ((long long)bb * 256 + threadIdx.x) * 8;
    const f32x4* ip = (const f32x4*)(in + e);
    f32x4 x = ip[0], y = ip[1];
    bf16x8 o;
#pragma unroll
    for (int j = 0; j < 4; ++j) { o[j] = (__bf16)x[j]; o[j + 4] = (__bf16)y[j]; }
    *(bf16x8*)(out + e) = o;
  }
}

// ---------------- merged QKV GEMM: 256x256 block, BK=32, per-wave 128x64 -------------
// 8 waves (2m x 4n), acc[8][4]: 12 ds_read_b128 per 32 MFMA (0.375 reads/MFMA vs 0.5
// at 64x64) -> cuts the dominant LDS-read-pipe term ~25%. Protocol = r14 verbatim
// (pinned fine-interleave, counted vmcnt, 3 buffers, 2-deep prefetch); swizzle =
// r15-proven BK=32 chunk-XOR c^=(row>>1)&3 (2-way = free).
__global__ __launch_bounds__(512, 2) void gemm_qkv(const __bf16* __restrict__ A,
                                                   const __bf16* __restrict__ Bw,
                                                   const float* __restrict__ qbias,
                                                   const float* __restrict__ vbias,
                                                   __bf16* __restrict__ Qo,
                                                   __bf16* __restrict__ Ko,
                                                   __bf16* __restrict__ Vto,
                                                   float sq) {
  __shared__ __align__(16) __bf16 lds[3 * 16384];  // per buf: A[256][32] @0, B[256][32] @8192
  const int tid = threadIdx.x;
  const int lane = tid & 63, wave = tid >> 6;
  const int wrow = wave >> 2, wcol = wave & 3;     // 2m x 4n of 128x64
  const int r = lane & 15, g = lane >> 4;

  // grid 360 = 8 XCD * (3 m-tiles x 15 n-tiles); per-XCD X patch 1.97MB L2-resident
  const int orig = blockIdx.x;
  const int xcd = orig & 7, ii = orig >> 3;        // ii in [0,45)
  const int m_idx = xcd * 3 + ii % 3;              // [0,24)
  const int n_idx = ii / 3;                        // [0,15)
  const int m0 = m_idx * 256, n0 = n_idx * 256;

  const f32x4 fz = {0.f, 0.f, 0.f, 0.f};
  f32x4 acc[8][4];
#pragma unroll
  for (int mi = 0; mi < 8; ++mi)
#pragma unroll
    for (int ni = 0; ni < 4; ++ni) acc[mi][ni] = fz;

  // staging sources, chunk pre-swizzled: LDS(row,c) holds global chunk c^((row>>1)&3)
  const __bf16* srcA[2];
  const __bf16* srcB[2];
#pragma unroll
  for (int j = 0; j < 2; ++j) {
    const int s = j * 512 + tid;
    const int row = s >> 2, ch = s & 3;
    const int sw = (ch ^ ((row >> 1) & 3)) * 8;
    srcA[j] = A + (size_t)(m0 + row) * 1280 + sw;
    srcB[j] = Bw + (size_t)(n0 + row) * 1280 + sw;
  }
  const int wd = wave * 512;

  auto stage = [&](int buf, int kt2) {
    const int k0 = kt2 * 32;
    __bf16* L = &lds[buf * 16384];
    glds16(srcA[0] + k0, L + wd);
    glds16(srcA[1] + k0, L + 4096 + wd);
    glds16(srcB[0] + k0, L + 8192 + wd);
    glds16(srcB[1] + k0, L + 12288 + wd);
  };

  // prologue: tiles 0 and 1 in flight; wait for tile 0 (oldest 4)
  stage(0, 0);
  stage(1, 1);
  asm volatile("s_waitcnt vmcnt(4)" ::: "memory");
  SB0();
  __builtin_amdgcn_s_barrier();
  SB0();

  const int aoff = (wrow * 128 + r) * 32;          // + mi*512
  const int boff = 8192 + (wcol * 64 + r) * 32;    // + ni*512
  const int csw = (g ^ ((r >> 1) & 3)) * 8;        // swizzled read chunk

  int cur = 0;
  for (int kt = 0; kt < 40; ++kt) {
    int nxt2 = cur + 2; if (nxt2 >= 3) nxt2 -= 3;
    const __bf16* Lb = &lds[cur * 16384];
    const bool pf = (kt + 2 < 40);

    bf16x8 af[8], bfr[4];
#pragma unroll
    for (int mi = 0; mi < 8; ++mi) af[mi] = *(const bf16x8*)&Lb[aoff + mi * 512 + csw];
#pragma unroll
    for (int ni = 0; ni < 4; ++ni) bfr[ni] = *(const bf16x8*)&Lb[boff + ni * 512 + csw];
    if (pf) stage(nxt2, kt + 2);
    asm volatile("s_waitcnt lgkmcnt(0)" ::: "memory");
    SB0();
    __builtin_amdgcn_s_setprio(1);
#pragma unroll
    for (int mi = 0; mi < 8; ++mi)
#pragma unroll
      for (int ni = 0; ni < 4; ++ni)
        acc[mi][ni] = mfma_bf16(af[mi], bfr[ni], acc[mi][ni]);
    __builtin_amdgcn_s_setprio(0);

    // tile kt+1's loads (issued last iter) must land; kt+2's 4 stay in flight
    if (pf) asm volatile("s_waitcnt vmcnt(4)" ::: "memory");
    else    asm volatile("s_waitcnt vmcnt(0)" ::: "memory");
    SB0();
    __builtin_amdgcn_s_barrier();
    SB0();
    cur = cur + 1; if (cur >= 3) cur -= 3;
  }

  const int which = n_idx / 5;                     // 0=Q 1=K 2=V (block-uniform)
  const int nb = n_idx * 256 - which * 1280 + wcol * 64;
  const float scale = (which == 0) ? sq : 1.f;

#pragma unroll
  for (int ni = 0; ni < 4; ++ni) {
    const int col = nb + ni * 16 + r;
    const float bv = (which == 0) ? qbias[col] : (which == 2) ? vbias[col] : 0.f;
#pragma unroll
    for (int mi = 0; mi < 8; ++mi) {
      if (which == 2) {
        const int row0 = m0 + wrow * 128 + mi * 16 + g * 4;
        if (row0 < 6000) {
          const int bidx = row0 / 1500;            // 4-row group never straddles
          const int t = row0 - bidx * 1500;
          union { __bf16 h[4]; unsigned long long u; } pk;
#pragma unroll
          for (int rr = 0; rr < 4; ++rr) pk.h[rr] = (__bf16)(acc[mi][ni][rr] + bv);
          *(unsigned long long*)&Vto[((size_t)(bidx * 1280 + col)) * 1536 + t] = pk.u;
        }
      } else {
        __bf16* dst = (which == 0) ? Qo : Ko;
#pragma unroll
        for (int rr = 0; rr < 4; ++rr) {
          const int row = m0 + wrow * 128 + mi * 16 + g * 4 + rr;
          dst[(size_t)row * 1280 + col] = (__bf16)((acc[mi][ni][rr] + bv) * scale);
        }
      }
    }
  }
}

// ---------------- O-projection GEMM, fine-interleaved BK=64 (r14, proven) ------------
__global__ __launch_bounds__(512, 2) void gemm_o(const __bf16* __restrict__ A,
                                                 const __bf16* __restrict__ Bw,
                                                 const float* __restrict__ bias,
                                                 float* __restrict__ out) {
  __shared__ __align__(16) __bf16 lds[3 * 24576];
  const int tid = threadIdx.x;
  const int lane = tid & 63, wave = tid >> 6;
  const int wrow = wave >> 2, wcol = wave & 3;
  const int r = lane & 15, g = lane >> 4;

  const int orig = blockIdx.x;
  const int xcd = orig & 7, ii = orig >> 3;     // ii in [0,30)
  const int m_idx = xcd * 6 + ii % 6;
  const int n_idx = ii / 6;                     // [0,5)
  const int m0 = m_idx * 128, n0 = n_idx * 256;

  const f32x4 fz = {0.f, 0.f, 0.f, 0.f};
  f32x4 acc[4][4];
#pragma unroll
  for (int mi = 0; mi < 4; ++mi)
#pragma unroll
    for (int ni = 0; ni < 4; ++ni) acc[mi][ni] = fz;

  const __bf16* srcA[2];
  const __bf16* srcB[4];
#pragma unroll
  for (int j = 0; j < 2; ++j) {
    const int slot = j * 512 + tid;
    const int row = slot >> 3, ch = slot & 7;
    srcA[j] = A + (size_t)(m0 + row) * 1280 + (ch ^ (row & 7)) * 8;
  }
#pragma unroll
  for (int j = 0; j < 4; ++j) {
    const int slot = j * 512 + tid;
    const int row = slot >> 3, ch = slot & 7;
    srcB[j] = Bw + (size_t)(n0 + row) * 1280 + (ch ^ (row & 7)) * 8;
  }
  const int wdst = wave * 512;

  auto stage_h0 = [&](int buf, int kt2) {
    const int k0 = kt2 * 64;
    glds16(srcA[0] + k0, &lds[buf * 24576 + wdst]);
    glds16(srcA[1] + k0, &lds[buf * 24576 + 4096 + wdst]);
    glds16(srcB[0] + k0, &lds[buf * 24576 + 8192 + wdst]);
  };
  auto stage_h1 = [&](int buf, int kt2) {
    const int k0 = kt2 * 64;
    glds16(srcB[1] + k0, &lds[buf * 24576 + 12288 + wdst]);
    glds16(srcB[2] + k0, &lds[buf * 24576 + 16384 + wdst]);
    glds16(srcB[3] + k0, &lds[buf * 24576 + 20480 + wdst]);
  };

  stage_h0(0, 0); stage_h1(0, 0);
  stage_h0(1, 1); stage_h1(1, 1);
  asm volatile("s_waitcnt vmcnt(6)" ::: "memory");
  SB0();
  __builtin_amdgcn_s_barrier();
  SB0();

  const int aoff = (wrow * 64 + r) * 64;
  const int boff = 8192 + (wcol * 64 + r) * 64;
  const int c0 = (g ^ (r & 7)) * 8;
  const int c1 = ((4 + g) ^ (r & 7)) * 8;

  int cur = 0;
  for (int kt = 0; kt < 20; ++kt) {
    int nxt2 = cur + 2; if (nxt2 >= 3) nxt2 -= 3;
    const __bf16* Lb = &lds[cur * 24576];
    const bool pf = (kt + 2 < 20);

    bf16x8 af[4], bfr[4];
#pragma unroll
    for (int mi = 0; mi < 4; ++mi) af[mi] = *(const bf16x8*)&Lb[aoff + mi * 1024 + c0];
#pragma unroll
    for (int ni = 0; ni < 4; ++ni) bfr[ni] = *(const bf16x8*)&Lb[boff + ni * 1024 + c0];
    if (pf) stage_h0(nxt2, kt + 2);
    asm volatile("s_waitcnt lgkmcnt(0)" ::: "memory");
    SB0();
    __builtin_amdgcn_s_setprio(1);
#pragma unroll
    for (int mi = 0; mi < 4; ++mi)
#pragma unroll
      for (int ni = 0; ni < 4; ++ni)
        acc[mi][ni] = mfma_bf16(af[mi], bfr[ni], acc[mi][ni]);
    __builtin_amdgcn_s_setprio(0);

    bf16x8 af1[4], bfr1[4];
#pragma unroll
    for (int mi = 0; mi < 4; ++mi) af1[mi] = *(const bf16x8*)&Lb[aoff + mi * 1024 + c1];
#pragma unroll
    for (int ni = 0; ni < 4; ++ni) bfr1[ni] = *(const bf16x8*)&Lb[boff + ni * 1024 + c1];
    if (pf) stage_h1(nxt2, kt + 2);
    asm volatile("s_waitcnt lgkmcnt(0)" ::: "memory");
    SB0();
    __builtin_amdgcn_s_setprio(1);
#pragma unroll
    for (int mi = 0; mi < 4; ++mi)
#pragma unroll
      for (int ni = 0; ni < 4; ++ni)
        acc[mi][ni] = mfma_bf16(af1[mi], bfr1[ni], acc[mi][ni]);
    __builtin_amdgcn_s_setprio(0);

    if (pf) asm volatile("s_waitcnt vmcnt(6)" ::: "memory");
    else    asm volatile("s_waitcnt vmcnt(0)" ::: "memory");
    SB0();
    __builtin_amdgcn_s_barrier();
    SB0();
    cur = cur + 1; if (cur >= 3) cur -= 3;
  }

#pragma unroll
  for (int ni = 0; ni < 4; ++ni) {
    const int col = n0 + wcol * 64 + ni * 16 + r;
    const float bv = bias[col];
#pragma unroll
    for (int mi = 0; mi < 4; ++mi) {
#pragma unroll
      for (int rr = 0; rr < 4; ++rr) {
        const int row = m0 + wrow * 64 + mi * 16 + g * 4 + rr;
        if (row < 6000) out[(size_t)row * 1280 + col] = acc[mi][ni][rr] + bv;
      }
    }
  }
}

// ---------------- flash attention: 4 waves x 64 q-rows (r14, proven) -----------------
__global__ __launch_bounds__(256, 2) void flash_attn(const __bf16* __restrict__ Qg,
                                                     const __bf16* __restrict__ Kg,
                                                     const __bf16* __restrict__ Vt,
                                                     __bf16* __restrict__ Og) {
  constexpr int TQ = 1500, NKT = 24;
  __shared__ __align__(16) __bf16 lds[18432];

  const int tid = threadIdx.x;
  const int lane = tid & 63, w = tid >> 6;
  const int r = lane & 15, g = lane >> 4;

  const int orig = blockIdx.x;
  const int work = (orig & 7) * 60 + (orig >> 3);
  const int bh = work / 6, qb = work - bh * 6;
  const int b = bh / 20, h = bh - b * 20;
  const int q0 = qb * 256;
  const size_t base = (size_t)b * (TQ * 1280) + h * 64;
  const __bf16* Vt_bh = Vt + (size_t)(b * 1280 + h * 64) * 1536;

  const int k_src_col = 8 * ((lane & 7) ^ (lane >> 3));
  const int k_row_loc = w * 8 + (lane >> 3);
  const int v_d_loc = 8 * w + (lane >> 3);
  const int v_chunk = 8 * ((lane & 7) ^ (lane >> 3));

  bf16x8 qf[4][2];
#pragma unroll
  for (int qs = 0; qs < 4; ++qs) {
    int t = q0 + w * 64 + qs * 16 + r;
    t = t < TQ ? t : TQ - 1;
    const __bf16* qp = Qg + base + (size_t)t * 1280;
#pragma unroll
    for (int dk = 0; dk < 2; ++dk) qf[qs][dk] = *(const bf16x8*)(qp + dk * 32 + g * 8);
  }

  bf16x8 ones;
#pragma unroll
  for (int j = 0; j < 8; ++j) ones[j] = (__bf16)1.0f;

  const f32x4 fz = {0.f, 0.f, 0.f, 0.f};
  f32x4 o_acc[4][4], o_sum[4];
#pragma unroll
  for (int qs = 0; qs < 4; ++qs) {
    o_sum[qs] = fz;
#pragma unroll
    for (int ni = 0; ni < 4; ++ni) o_acc[qs][ni] = fz;
  }

  auto stage = [&](int buf, int kt2) {
    const int kb = kt2 * 64;
#pragma unroll
    for (int i = 0; i < 2; ++i) {
      int row = kb + i * 32 + k_row_loc;
      row = row < TQ ? row : TQ - 1;
      glds16(Kg + base + (size_t)row * 1280 + k_src_col,
             &lds[buf * 8192 + i * 2048 + w * 512]);
    }
#pragma unroll
    for (int i = 0; i < 2; ++i) {
      glds16(Vt_bh + (size_t)(32 * i + v_d_loc) * 1536 + kb + v_chunk,
             &lds[buf * 8192 + 4096 + i * 2048 + w * 512]);
    }
  };

  stage(0, 0);
  __syncthreads();
  for (int kt = 0; kt < NKT; ++kt) {
    const int cur = kt & 1;
    if (kt + 1 < NKT) stage(cur ^ 1, kt + 1);

    const __bf16* Kb = &lds[cur * 8192];

    f32x4 s[4][4];
#pragma unroll
    for (int qs = 0; qs < 4; ++qs)
#pragma unroll
      for (int nt = 0; nt < 4; ++nt) s[qs][nt] = fz;
#pragma unroll
    for (int dk = 0; dk < 2; ++dk) {
      bf16x8 kf[4];
#pragma unroll
      for (int nt = 0; nt < 4; ++nt) {
        const int row = nt * 16 + r;
        const int sc = (dk * 32 + g * 8) ^ ((r & 7) << 3);
        kf[nt] = *(const bf16x8*)&Kb[row * 64 + sc];
      }
      __builtin_amdgcn_s_setprio(1);
#pragma unroll
      for (int qs = 0; qs < 4; ++qs)
#pragma unroll
        for (int nt = 0; nt < 4; ++nt) s[qs][nt] = mfma_bf16(kf[nt], qf[qs][dk], s[qs][nt]);
      __builtin_amdgcn_s_setprio(0);
    }

    if (kt == NKT - 1) {
#pragma unroll
      for (int nt = 0; nt < 4; ++nt)
#pragma unroll
        for (int rr = 0; rr < 4; ++rr) {
          const int key = kt * 64 + nt * 16 + g * 4 + rr;
          if (key >= TQ) {
#pragma unroll
            for (int qs = 0; qs < 4; ++qs) s[qs][nt][rr] = -1.0e30f;
          }
        }
    }

#pragma unroll
    for (int qs = 0; qs < 4; ++qs)
#pragma unroll
      for (int nt = 0; nt < 4; ++nt)
#pragma unroll
        for (int rr = 0; rr < 4; ++rr)
          s[qs][nt][rr] = fast_exp2(s[qs][nt][rr]);

    const __bf16* Vbuf = &lds[cur * 8192 + 4096];
    const int swz = (r & 7) << 3;
#pragma unroll
    for (int ks = 0; ks < 2; ++ks) {
      bf16x8 pa[4];
#pragma unroll
      for (int qs = 0; qs < 4; ++qs) {
        bf16x8 t;
#pragma unroll
        for (int j = 0; j < 4; ++j) {
          t[j] = (__bf16)s[qs][2 * ks][j];
          t[4 + j] = (__bf16)s[qs][2 * ks + 1][j];
        }
        pa[qs] = t;
      }
      const int o1 = (32 * ks + 4 * g) ^ swz;
      const int o2 = (32 * ks + 16 + 4 * g) ^ swz;
      __builtin_amdgcn_s_setprio(1);
#pragma unroll
      for (int qs = 0; qs < 4; ++qs) o_sum[qs] = mfma_bf16(ones, pa[qs], o_sum[qs]);
#pragma unroll
      for (int ni = 0; ni < 4; ++ni) {
        const int dbase = (16 * ni + r) * 64;
        union { bf16x4 hh[2]; bf16x8 v; } u;
        u.hh[0] = *(const bf16x4*)&Vbuf[dbase + o1];
        u.hh[1] = *(const bf16x4*)&Vbuf[dbase + o2];
#pragma unroll
        for (int qs = 0; qs < 4; ++qs) o_acc[qs][ni] = mfma_bf16(u.v, pa[qs], o_acc[qs][ni]);
      }
      __builtin_amdgcn_s_setprio(0);
    }

    __syncthreads();
  }

  float inv[4];
#pragma unroll
  for (int qs = 0; qs < 4; ++qs) inv[qs] = 1.0f / o_sum[qs][0];

  __bf16* Ob = &lds[w * 4608];
#pragma unroll
  for (int qs = 0; qs < 4; ++qs) {
#pragma unroll
    for (int ni = 0; ni < 4; ++ni)
#pragma unroll
      for (int rr = 0; rr < 4; ++rr)
        Ob[(qs * 16 + r) * 72 + ni * 16 + g * 4 + rr] = (__bf16)(o_acc[qs][ni][rr] * inv[qs]);
  }
  __syncthreads();
  const int qg = q0 + w * 64 + lane;
  if (qg < TQ) {
#pragma unroll
    for (int v = 0; v < 8; ++v) {
      const int c = v * 8;
      bf16x8 val = *(const bf16x8*)&lds[w * 4608 + lane * 72 + c];
      *(bf16x8*)&Og[base + (size_t)qg * 1280 + c] = val;
    }
  }
}

// ---------------- launcher ----------------
extern "C" void kernel_launch(void* const* d_in, const int* in_sizes, int n_in,
                              void* d_out, int out_size, void* d_ws, size_t ws_size,
                              hipStream_t stream) {
  const float* hs = (const float*)d_in[0];
  const float* qw = (const float*)d_in[1];
  const float* qb = (const float*)d_in[2];
  const float* kw = (const float*)d_in[3];
  const float* vw = (const float*)d_in[4];
  const float* vb = (const float*)d_in[5];
  const float* ow = (const float*)d_in[6];
  const float* ob = (const float*)d_in[7];

  const long long MP = 6144LL * 1280;  // == 5120 * 1536 (Vt reuses this slot)
  const long long WE = 1280LL * 1280;
  __bf16* Xb = (__bf16*)d_ws;
  __bf16* Wq = Xb + MP;   // Wq/Wk/Wv contiguous -> single [3840][1280] B matrix
  __bf16* Wk = Wq + WE;
  __bf16* Wv = Wk + WE;
  __bf16* Wo = Wv + WE;
  __bf16* Qb = Wo + WE;
  __bf16* Kb = Qb + MP;
  __bf16* Vtb = Kb + MP;
  __bf16* Ab = Xb;  // alias: X dead after QKV projection

  cvt_all<<<7040, 256, 0, stream>>>(hs, qw, kw, vw, ow, Xb, Wq, Wk, Wv, Wo);

  const float SQ = 1.4426950408889634f / 64.f;  // log2(e) / sqrt(64)^2
  gemm_qkv<<<360, 512, 0, stream>>>(Xb, Wq, qb, vb, Qb, Kb, Vtb, SQ);

  flash_attn<<<480, 256, 0, stream>>>(Qb, Kb, Vtb, Ab);

  gemm_o<<<240, 512, 0, stream>>>(Ab, Wo, ob, (float*)d_out);
}

// Round 20
// 156.522 us; speedup vs baseline: 1.1207x; 1.1207x over previous
//
#include <hip/hip_runtime.h>

typedef __attribute__((ext_vector_type(4))) float f32x4;
typedef __attribute__((ext_vector_type(8))) __bf16 bf16x8;
typedef __attribute__((ext_vector_type(4))) __bf16 bf16x4;

#define DEV __device__ __forceinline__

DEV f32x4 mfma_bf16(bf16x8 a, bf16x8 b, f32x4 c) {
  return __builtin_amdgcn_mfma_f32_16x16x32_bf16(a, b, c, 0, 0, 0);
}

DEV void glds16(const void* gp, void* lp) {
  __builtin_amdgcn_global_load_lds((const __attribute__((address_space(1))) void*)gp,
                                   (__attribute__((address_space(3))) void*)lp, 16, 0, 0);
}

DEV float fast_exp2(float x) {
#if __has_builtin(__builtin_amdgcn_exp2f)
  return __builtin_amdgcn_exp2f(x);
#else
  float r;
  asm("v_exp_f32 %0, %1" : "=v"(r) : "v"(x));
  return r;
#endif
}

#define SB0() __builtin_amdgcn_sched_barrier(0)

// r20 = exact revert to r14/r18 (best verified: 156.6 us, reproduced twice).
// Full ledger: r15 BK=32/2-blocks null; r16 unpinned worse; r17 8-phase much worse;
// r19 per-wave 128x64 worse. The pinned fine-interleaved counted schedule is the
// verified optimum of every structure family explored this session.

// ---------------- fused f32->bf16 conversions ----------------
__global__ __launch_bounds__(256) void cvt_all(const float* __restrict__ hs,
                                               const float* __restrict__ qw,
                                               const float* __restrict__ kw,
                                               const float* __restrict__ vw,
                                               const float* __restrict__ ow,
                                               __bf16* __restrict__ oX,
                                               __bf16* __restrict__ oQ,
                                               __bf16* __restrict__ oK,
                                               __bf16* __restrict__ oV,
                                               __bf16* __restrict__ oO) {
  const int blk = blockIdx.x;
  if (blk < 3840) {
    long long e = ((long long)blk * 256 + threadIdx.x) * 8;
    bf16x8 o = {};
    if (e < 7680000) {
      const f32x4* ip = (const f32x4*)(hs + e);
      f32x4 a = ip[0], b = ip[1];
#pragma unroll
      for (int j = 0; j < 4; ++j) { o[j] = (__bf16)a[j]; o[j + 4] = (__bf16)b[j]; }
    }
    *(bf16x8*)(oX + e) = o;
  } else {
    const int wb = blk - 3840;
    const int which = wb / 800;
    const int bb = wb - which * 800;
    const float* in = which == 0 ? qw : which == 1 ? kw : which == 2 ? vw : ow;
    __bf16* out = which == 0 ? oQ : which == 1 ? oK : which == 2 ? oV : oO;
    long long e = ((long long)bb * 256 + threadIdx.x) * 8;
    const f32x4* ip = (const f32x4*)(in + e);
    f32x4 x = ip[0], y = ip[1];
    bf16x8 o;
#pragma unroll
    for (int j = 0; j < 4; ++j) { o[j] = (__bf16)x[j]; o[j + 4] = (__bf16)y[j]; }
    *(bf16x8*)(out + e) = o;
  }
}

// ---------------- merged QKV GEMM, fine-interleaved counted schedule (r9/r14) --------
__global__ __launch_bounds__(512, 2) void gemm_qkv(const __bf16* __restrict__ A,
                                                   const __bf16* __restrict__ Bw,
                                                   const float* __restrict__ qbias,
                                                   const float* __restrict__ vbias,
                                                   __bf16* __restrict__ Qo,
                                                   __bf16* __restrict__ Ko,
                                                   __bf16* __restrict__ Vto,
                                                   float sq) {
  __shared__ __align__(16) __bf16 lds[3 * 24576];
  const int tid = threadIdx.x;
  const int lane = tid & 63, wave = tid >> 6;
  const int wrow = wave >> 2, wcol = wave & 3;
  const int r = lane & 15, g = lane >> 4;

  const int orig = blockIdx.x;
  const int xcd = orig & 7, ii = orig >> 3;     // ii in [0,90)
  const int m_idx = xcd * 6 + ii % 6;
  const int n_idx = ii / 6;
  const int m0 = m_idx * 128, n0 = n_idx * 256;

  const f32x4 fz = {0.f, 0.f, 0.f, 0.f};
  f32x4 acc[4][4];
#pragma unroll
  for (int mi = 0; mi < 4; ++mi)
#pragma unroll
    for (int ni = 0; ni < 4; ++ni) acc[mi][ni] = fz;

  const __bf16* srcA[2];
  const __bf16* srcB[4];
#pragma unroll
  for (int j = 0; j < 2; ++j) {
    const int slot = j * 512 + tid;
    const int row = slot >> 3, ch = slot & 7;
    srcA[j] = A + (size_t)(m0 + row) * 1280 + (ch ^ (row & 7)) * 8;
  }
#pragma unroll
  for (int j = 0; j < 4; ++j) {
    const int slot = j * 512 + tid;
    const int row = slot >> 3, ch = slot & 7;
    srcB[j] = Bw + (size_t)(n0 + row) * 1280 + (ch ^ (row & 7)) * 8;
  }
  const int wdst = wave * 512;

  auto stage_h0 = [&](int buf, int kt2) {
    const int k0 = kt2 * 64;
    glds16(srcA[0] + k0, &lds[buf * 24576 + wdst]);
    glds16(srcA[1] + k0, &lds[buf * 24576 + 4096 + wdst]);
    glds16(srcB[0] + k0, &lds[buf * 24576 + 8192 + wdst]);
  };
  auto stage_h1 = [&](int buf, int kt2) {
    const int k0 = kt2 * 64;
    glds16(srcB[1] + k0, &lds[buf * 24576 + 12288 + wdst]);
    glds16(srcB[2] + k0, &lds[buf * 24576 + 16384 + wdst]);
    glds16(srcB[3] + k0, &lds[buf * 24576 + 20480 + wdst]);
  };

  stage_h0(0, 0); stage_h1(0, 0);
  stage_h0(1, 1); stage_h1(1, 1);
  asm volatile("s_waitcnt vmcnt(6)" ::: "memory");
  SB0();
  __builtin_amdgcn_s_barrier();
  SB0();

  const int aoff = (wrow * 64 + r) * 64;
  const int boff = 8192 + (wcol * 64 + r) * 64;
  const int c0 = (g ^ (r & 7)) * 8;
  const int c1 = ((4 + g) ^ (r & 7)) * 8;

  int cur = 0;
  for (int kt = 0; kt < 20; ++kt) {
    int nxt2 = cur + 2; if (nxt2 >= 3) nxt2 -= 3;
    const __bf16* Lb = &lds[cur * 24576];
    const bool pf = (kt + 2 < 20);

    bf16x8 af[4], bfr[4];
#pragma unroll
    for (int mi = 0; mi < 4; ++mi) af[mi] = *(const bf16x8*)&Lb[aoff + mi * 1024 + c0];
#pragma unroll
    for (int ni = 0; ni < 4; ++ni) bfr[ni] = *(const bf16x8*)&Lb[boff + ni * 1024 + c0];
    if (pf) stage_h0(nxt2, kt + 2);
    asm volatile("s_waitcnt lgkmcnt(0)" ::: "memory");
    SB0();
    __builtin_amdgcn_s_setprio(1);
#pragma unroll
    for (int mi = 0; mi < 4; ++mi)
#pragma unroll
      for (int ni = 0; ni < 4; ++ni)
        acc[mi][ni] = mfma_bf16(af[mi], bfr[ni], acc[mi][ni]);
    __builtin_amdgcn_s_setprio(0);

    bf16x8 af1[4], bfr1[4];
#pragma unroll
    for (int mi = 0; mi < 4; ++mi) af1[mi] = *(const bf16x8*)&Lb[aoff + mi * 1024 + c1];
#pragma unroll
    for (int ni = 0; ni < 4; ++ni) bfr1[ni] = *(const bf16x8*)&Lb[boff + ni * 1024 + c1];
    if (pf) stage_h1(nxt2, kt + 2);
    asm volatile("s_waitcnt lgkmcnt(0)" ::: "memory");
    SB0();
    __builtin_amdgcn_s_setprio(1);
#pragma unroll
    for (int mi = 0; mi < 4; ++mi)
#pragma unroll
      for (int ni = 0; ni < 4; ++ni)
        acc[mi][ni] = mfma_bf16(af1[mi], bfr1[ni], acc[mi][ni]);
    __builtin_amdgcn_s_setprio(0);

    if (pf) asm volatile("s_waitcnt vmcnt(6)" ::: "memory");
    else    asm volatile("s_waitcnt vmcnt(0)" ::: "memory");
    SB0();
    __builtin_amdgcn_s_barrier();
    SB0();
    cur = cur + 1; if (cur >= 3) cur -= 3;
  }

  const int which = n_idx / 5;
  const int nb = n0 - which * 1280 + wcol * 64;
  const float scale = (which == 0) ? sq : 1.f;

#pragma unroll
  for (int ni = 0; ni < 4; ++ni) {
    const int col = nb + ni * 16 + r;
    const float bv = (which == 0) ? qbias[col] : (which == 2) ? vbias[col] : 0.f;
#pragma unroll
    for (int mi = 0; mi < 4; ++mi) {
      if (which == 2) {
        const int row0 = m0 + wrow * 64 + mi * 16 + g * 4;
        if (row0 < 6000) {
          const int bidx = row0 / 1500;
          const int t = row0 - bidx * 1500;
          union { __bf16 h[4]; unsigned long long u; } pk;
#pragma unroll
          for (int rr = 0; rr < 4; ++rr) pk.h[rr] = (__bf16)(acc[mi][ni][rr] + bv);
          *(unsigned long long*)&Vto[((size_t)(bidx * 1280 + col)) * 1536 + t] = pk.u;
        }
      } else {
        __bf16* dst = (which == 0) ? Qo : Ko;
#pragma unroll
        for (int rr = 0; rr < 4; ++rr) {
          const int row = m0 + wrow * 64 + mi * 16 + g * 4 + rr;
          dst[(size_t)row * 1280 + col] = (__bf16)((acc[mi][ni][rr] + bv) * scale);
        }
      }
    }
  }
}

// ---------------- O-projection GEMM, same fine-interleaved structure, f32 epilogue ----
__global__ __launch_bounds__(512, 2) void gemm_o(const __bf16* __restrict__ A,
                                                 const __bf16* __restrict__ Bw,
                                                 const float* __restrict__ bias,
                                                 float* __restrict__ out) {
  __shared__ __align__(16) __bf16 lds[3 * 24576];
  const int tid = threadIdx.x;
  const int lane = tid & 63, wave = tid >> 6;
  const int wrow = wave >> 2, wcol = wave & 3;
  const int r = lane & 15, g = lane >> 4;

  const int orig = blockIdx.x;
  const int xcd = orig & 7, ii = orig >> 3;     // ii in [0,30)
  const int m_idx = xcd * 6 + ii % 6;
  const int n_idx = ii / 6;                     // [0,5)
  const int m0 = m_idx * 128, n0 = n_idx * 256;

  const f32x4 fz = {0.f, 0.f, 0.f, 0.f};
  f32x4 acc[4][4];
#pragma unroll
  for (int mi = 0; mi < 4; ++mi)
#pragma unroll
    for (int ni = 0; ni < 4; ++ni) acc[mi][ni] = fz;

  const __bf16* srcA[2];
  const __bf16* srcB[4];
#pragma unroll
  for (int j = 0; j < 2; ++j) {
    const int slot = j * 512 + tid;
    const int row = slot >> 3, ch = slot & 7;
    srcA[j] = A + (size_t)(m0 + row) * 1280 + (ch ^ (row & 7)) * 8;
  }
#pragma unroll
  for (int j = 0; j < 4; ++j) {
    const int slot = j * 512 + tid;
    const int row = slot >> 3, ch = slot & 7;
    srcB[j] = Bw + (size_t)(n0 + row) * 1280 + (ch ^ (row & 7)) * 8;
  }
  const int wdst = wave * 512;

  auto stage_h0 = [&](int buf, int kt2) {
    const int k0 = kt2 * 64;
    glds16(srcA[0] + k0, &lds[buf * 24576 + wdst]);
    glds16(srcA[1] + k0, &lds[buf * 24576 + 4096 + wdst]);
    glds16(srcB[0] + k0, &lds[buf * 24576 + 8192 + wdst]);
  };
  auto stage_h1 = [&](int buf, int kt2) {
    const int k0 = kt2 * 64;
    glds16(srcB[1] + k0, &lds[buf * 24576 + 12288 + wdst]);
    glds16(srcB[2] + k0, &lds[buf * 24576 + 16384 + wdst]);
    glds16(srcB[3] + k0, &lds[buf * 24576 + 20480 + wdst]);
  };

  stage_h0(0, 0); stage_h1(0, 0);
  stage_h0(1, 1); stage_h1(1, 1);
  asm volatile("s_waitcnt vmcnt(6)" ::: "memory");
  SB0();
  __builtin_amdgcn_s_barrier();
  SB0();

  const int aoff = (wrow * 64 + r) * 64;
  const int boff = 8192 + (wcol * 64 + r) * 64;
  const int c0 = (g ^ (r & 7)) * 8;
  const int c1 = ((4 + g) ^ (r & 7)) * 8;

  int cur = 0;
  for (int kt = 0; kt < 20; ++kt) {
    int nxt2 = cur + 2; if (nxt2 >= 3) nxt2 -= 3;
    const __bf16* Lb = &lds[cur * 24576];
    const bool pf = (kt + 2 < 20);

    bf16x8 af[4], bfr[4];
#pragma unroll
    for (int mi = 0; mi < 4; ++mi) af[mi] = *(const bf16x8*)&Lb[aoff + mi * 1024 + c0];
#pragma unroll
    for (int ni = 0; ni < 4; ++ni) bfr[ni] = *(const bf16x8*)&Lb[boff + ni * 1024 + c0];
    if (pf) stage_h0(nxt2, kt + 2);
    asm volatile("s_waitcnt lgkmcnt(0)" ::: "memory");
    SB0();
    __builtin_amdgcn_s_setprio(1);
#pragma unroll
    for (int mi = 0; mi < 4; ++mi)
#pragma unroll
      for (int ni = 0; ni < 4; ++ni)
        acc[mi][ni] = mfma_bf16(af[mi], bfr[ni], acc[mi][ni]);
    __builtin_amdgcn_s_setprio(0);

    bf16x8 af1[4], bfr1[4];
#pragma unroll
    for (int mi = 0; mi < 4; ++mi) af1[mi] = *(const bf16x8*)&Lb[aoff + mi * 1024 + c1];
#pragma unroll
    for (int ni = 0; ni < 4; ++ni) bfr1[ni] = *(const bf16x8*)&Lb[boff + ni * 1024 + c1];
    if (pf) stage_h1(nxt2, kt + 2);
    asm volatile("s_waitcnt lgkmcnt(0)" ::: "memory");
    SB0();
    __builtin_amdgcn_s_setprio(1);
#pragma unroll
    for (int mi = 0; mi < 4; ++mi)
#pragma unroll
      for (int ni = 0; ni < 4; ++ni)
        acc[mi][ni] = mfma_bf16(af1[mi], bfr1[ni], acc[mi][ni]);
    __builtin_amdgcn_s_setprio(0);

    if (pf) asm volatile("s_waitcnt vmcnt(6)" ::: "memory");
    else    asm volatile("s_waitcnt vmcnt(0)" ::: "memory");
    SB0();
    __builtin_amdgcn_s_barrier();
    SB0();
    cur = cur + 1; if (cur >= 3) cur -= 3;
  }

#pragma unroll
  for (int ni = 0; ni < 4; ++ni) {
    const int col = n0 + wcol * 64 + ni * 16 + r;
    const float bv = bias[col];
#pragma unroll
    for (int mi = 0; mi < 4; ++mi) {
#pragma unroll
      for (int rr = 0; rr < 4; ++rr) {
        const int row = m0 + wrow * 64 + mi * 16 + g * 4 + rr;
        if (row < 6000) out[(size_t)row * 1280 + col] = acc[mi][ni][rr] + bv;
      }
    }
  }
}

// ---------------- flash attention: 4 waves x 64 q-rows (r14, proven) -----------------
__global__ __launch_bounds__(256, 2) void flash_attn(const __bf16* __restrict__ Qg,
                                                     const __bf16* __restrict__ Kg,
                                                     const __bf16* __restrict__ Vt,
                                                     __bf16* __restrict__ Og) {
  constexpr int TQ = 1500, NKT = 24;
  __shared__ __align__(16) __bf16 lds[18432];

  const int tid = threadIdx.x;
  const int lane = tid & 63, w = tid >> 6;
  const int r = lane & 15, g = lane >> 4;

  const int orig = blockIdx.x;
  const int work = (orig & 7) * 60 + (orig >> 3);
  const int bh = work / 6, qb = work - bh * 6;
  const int b = bh / 20, h = bh - b * 20;
  const int q0 = qb * 256;
  const size_t base = (size_t)b * (TQ * 1280) + h * 64;
  const __bf16* Vt_bh = Vt + (size_t)(b * 1280 + h * 64) * 1536;

  const int k_src_col = 8 * ((lane & 7) ^ (lane >> 3));
  const int k_row_loc = w * 8 + (lane >> 3);
  const int v_d_loc = 8 * w + (lane >> 3);
  const int v_chunk = 8 * ((lane & 7) ^ (lane >> 3));

  bf16x8 qf[4][2];
#pragma unroll
  for (int qs = 0; qs < 4; ++qs) {
    int t = q0 + w * 64 + qs * 16 + r;
    t = t < TQ ? t : TQ - 1;
    const __bf16* qp = Qg + base + (size_t)t * 1280;
#pragma unroll
    for (int dk = 0; dk < 2; ++dk) qf[qs][dk] = *(const bf16x8*)(qp + dk * 32 + g * 8);
  }

  bf16x8 ones;
#pragma unroll
  for (int j = 0; j < 8; ++j) ones[j] = (__bf16)1.0f;

  const f32x4 fz = {0.f, 0.f, 0.f, 0.f};
  f32x4 o_acc[4][4], o_sum[4];
#pragma unroll
  for (int qs = 0; qs < 4; ++qs) {
    o_sum[qs] = fz;
#pragma unroll
    for (int ni = 0; ni < 4; ++ni) o_acc[qs][ni] = fz;
  }

  auto stage = [&](int buf, int kt2) {
    const int kb = kt2 * 64;
#pragma unroll
    for (int i = 0; i < 2; ++i) {
      int row = kb + i * 32 + k_row_loc;
      row = row < TQ ? row : TQ - 1;
      glds16(Kg + base + (size_t)row * 1280 + k_src_col,
             &lds[buf * 8192 + i * 2048 + w * 512]);
    }
#pragma unroll
    for (int i = 0; i < 2; ++i) {
      glds16(Vt_bh + (size_t)(32 * i + v_d_loc) * 1536 + kb + v_chunk,
             &lds[buf * 8192 + 4096 + i * 2048 + w * 512]);
    }
  };

  stage(0, 0);
  __syncthreads();
  for (int kt = 0; kt < NKT; ++kt) {
    const int cur = kt & 1;
    if (kt + 1 < NKT) stage(cur ^ 1, kt + 1);

    const __bf16* Kb = &lds[cur * 8192];

    f32x4 s[4][4];
#pragma unroll
    for (int qs = 0; qs < 4; ++qs)
#pragma unroll
      for (int nt = 0; nt < 4; ++nt) s[qs][nt] = fz;
#pragma unroll
    for (int dk = 0; dk < 2; ++dk) {
      bf16x8 kf[4];
#pragma unroll
      for (int nt = 0; nt < 4; ++nt) {
        const int row = nt * 16 + r;
        const int sc = (dk * 32 + g * 8) ^ ((r & 7) << 3);
        kf[nt] = *(const bf16x8*)&Kb[row * 64 + sc];
      }
      __builtin_amdgcn_s_setprio(1);
#pragma unroll
      for (int qs = 0; qs < 4; ++qs)
#pragma unroll
        for (int nt = 0; nt < 4; ++nt) s[qs][nt] = mfma_bf16(kf[nt], qf[qs][dk], s[qs][nt]);
      __builtin_amdgcn_s_setprio(0);
    }

    if (kt == NKT - 1) {
#pragma unroll
      for (int nt = 0; nt < 4; ++nt)
#pragma unroll
        for (int rr = 0; rr < 4; ++rr) {
          const int key = kt * 64 + nt * 16 + g * 4 + rr;
          if (key >= TQ) {
#pragma unroll
            for (int qs = 0; qs < 4; ++qs) s[qs][nt][rr] = -1.0e30f;
          }
        }
    }

#pragma unroll
    for (int qs = 0; qs < 4; ++qs)
#pragma unroll
      for (int nt = 0; nt < 4; ++nt)
#pragma unroll
        for (int rr = 0; rr < 4; ++rr)
          s[qs][nt][rr] = fast_exp2(s[qs][nt][rr]);

    const __bf16* Vbuf = &lds[cur * 8192 + 4096];
    const int swz = (r & 7) << 3;
#pragma unroll
    for (int ks = 0; ks < 2; ++ks) {
      bf16x8 pa[4];
#pragma unroll
      for (int qs = 0; qs < 4; ++qs) {
        bf16x8 t;
#pragma unroll
        for (int j = 0; j < 4; ++j) {
          t[j] = (__bf16)s[qs][2 * ks][j];
          t[4 + j] = (__bf16)s[qs][2 * ks + 1][j];
        }
        pa[qs] = t;
      }
      const int o1 = (32 * ks + 4 * g) ^ swz;
      const int o2 = (32 * ks + 16 + 4 * g) ^ swz;
      __builtin_amdgcn_s_setprio(1);
#pragma unroll
      for (int qs = 0; qs < 4; ++qs) o_sum[qs] = mfma_bf16(ones, pa[qs], o_sum[qs]);
#pragma unroll
      for (int ni = 0; ni < 4; ++ni) {
        const int dbase = (16 * ni + r) * 64;
        union { bf16x4 hh[2]; bf16x8 v; } u;
        u.hh[0] = *(const bf16x4*)&Vbuf[dbase + o1];
        u.hh[1] = *(const bf16x4*)&Vbuf[dbase + o2];
#pragma unroll
        for (int qs = 0; qs < 4; ++qs) o_acc[qs][ni] = mfma_bf16(u.v, pa[qs], o_acc[qs][ni]);
      }
      __builtin_amdgcn_s_setprio(0);
    }

    __syncthreads();
  }

  float inv[4];
#pragma unroll
  for (int qs = 0; qs < 4; ++qs) inv[qs] = 1.0f / o_sum[qs][0];

  __bf16* Ob = &lds[w * 4608];
#pragma unroll
  for (int qs = 0; qs < 4; ++qs) {
#pragma unroll
    for (int ni = 0; ni < 4; ++ni)
#pragma unroll
      for (int rr = 0; rr < 4; ++rr)
        Ob[(qs * 16 + r) * 72 + ni * 16 + g * 4 + rr] = (__bf16)(o_acc[qs][ni][rr] * inv[qs]);
  }
  __syncthreads();
  const int qg = q0 + w * 64 + lane;
  if (qg < TQ) {
#pragma unroll
    for (int v = 0; v < 8; ++v) {
      const int c = v * 8;
      bf16x8 val = *(const bf16x8*)&lds[w * 4608 + lane * 72 + c];
      *(bf16x8*)&Og[base + (size_t)qg * 1280 + c] = val;
    }
  }
}

// ---------------- launcher ----------------
extern "C" void kernel_launch(void* const* d_in, const int* in_sizes, int n_in,
                              void* d_out, int out_size, void* d_ws, size_t ws_size,
                              hipStream_t stream) {
  const float* hs = (const float*)d_in[0];
  const float* qw = (const float*)d_in[1];
  const float* qb = (const float*)d_in[2];
  const float* kw = (const float*)d_in[3];
  const float* vw = (const float*)d_in[4];
  const float* vb = (const float*)d_in[5];
  const float* ow = (const float*)d_in[6];
  const float* ob = (const float*)d_in[7];

  const long long MP = 6144LL * 1280;  // == 5120 * 1536 (Vt reuses this slot)
  const long long WE = 1280LL * 1280;
  __bf16* Xb = (__bf16*)d_ws;
  __bf16* Wq = Xb + MP;   // Wq/Wk/Wv contiguous -> single [3840][1280] B matrix
  __bf16* Wk = Wq + WE;
  __bf16* Wv = Wk + WE;
  __bf16* Wo = Wv + WE;
  __bf16* Qb = Wo + WE;
  __bf16* Kb = Qb + MP;
  __bf16* Vtb = Kb + MP;
  __bf16* Ab = Xb;  // alias: X dead after QKV projection

  cvt_all<<<7040, 256, 0, stream>>>(hs, qw, kw, vw, ow, Xb, Wq, Wk, Wv, Wo);

  const float SQ = 1.4426950408889634f / 64.f;  // log2(e) / sqrt(64)^2
  gemm_qkv<<<720, 512, 0, stream>>>(Xb, Wq, qb, vb, Qb, Kb, Vtb, SQ);

  flash_attn<<<480, 256, 0, stream>>>(Qb, Kb, Vtb, Ab);

  gemm_o<<<240, 512, 0, stream>>>(Ab, Wo, ob, (float*)d_out);
}